// Round 14
// baseline (257.775 us; speedup 1.0000x reference)
//
#include <hip/hip_runtime.h>
#include <hip/hip_bf16.h>

#define N_NODES 100000
#define NE      1600000

#define BINSH 7
#define NBIN  782                      // ceil(100000 / 128)
#define BCAP  3072                     // max edges/bin (avg 2046, sigma~45)
#define SEPB  16384                    // edges per binning block
#define SC_BLKS ((NE + SEPB - 1) / SEPB)   // 98 scatter blocks
#define PRE_BLKS 512
#define AGG_EXTRA 208                  // aggcsr extra blocks: W-conv + mask
#define NMASKW 200000                  // 12.8M dropout bits / 64

typedef __attribute__((ext_vector_type(8))) short bfrag;   // 8 bf16 (4 VGPR)
typedef __attribute__((ext_vector_type(4))) float ffrag;   // 4 fp32 acc

#define BFLO(u) __uint_as_float((u) << 16)
#define BFHI(u) __uint_as_float((u) & 0xffff0000u)

// ---------------------------------------------------------------------------
// JAX threefry2x32, partitionable path. key=(0,42), counter=(0,f),
// bits = out0 ^ out1, keep <=> top bit == 0.
// ---------------------------------------------------------------------------
__device__ __forceinline__ unsigned tf_rotl(unsigned x, int d) {
    return (x << d) | (x >> (32 - d));
}

__device__ __forceinline__ unsigned tf_word(unsigned f) {
    const unsigned ks0 = 0u;
    const unsigned ks1 = 42u;
    const unsigned ks2 = 0x1BD11BDAu ^ 0u ^ 42u;
    unsigned x0 = 0u + ks0;
    unsigned x1 = f + ks1;
#define TF_RND(r) { x0 += x1; x1 = tf_rotl(x1, r); x1 ^= x0; }
    TF_RND(13) TF_RND(15) TF_RND(26) TF_RND(6)
    x0 += ks1; x1 += ks2 + 1u;
    TF_RND(17) TF_RND(29) TF_RND(16) TF_RND(24)
    x0 += ks2; x1 += ks0 + 2u;
    TF_RND(13) TF_RND(15) TF_RND(26) TF_RND(6)
    x0 += ks0; x1 += ks1 + 3u;
    TF_RND(17) TF_RND(29) TF_RND(16) TF_RND(24)
    x0 += ks1; x1 += ks2 + 4u;
    TF_RND(13) TF_RND(15) TF_RND(26) TF_RND(6)
    x0 += ks2; x1 += ks0 + 5u;
#undef TF_RND
    return x0 ^ x1;
}

__device__ __forceinline__ unsigned short bf_bits(float v) {
    __hip_bfloat16 b = __float2bfloat16(v);
    return *(unsigned short*)&b;
}

// ---------------------------------------------------------------------------
// FUSED preprocessing + binned edge scatter (512 blocks x 1024):
//   blocks 0..97:   per-block dtype probe + edge scatter into fixed-cap bins
//   blocks 98..511: x->bf16 (feeds aggcsr). W-conv + mask moved to aggcsr.
// ---------------------------------------------------------------------------
__global__ __launch_bounds__(1024) void k_prescatter(
    const int* __restrict__ ei, int* __restrict__ bincur, int* __restrict__ pairs,
    const float4* __restrict__ x4, ushort4* __restrict__ xb4) {
    const int t = threadIdx.x;

    if (blockIdx.x < SC_BLKS) {
        __shared__ int nz;
        __shared__ int h[NBIN];
        __shared__ int lbase[NBIN];
        if (t == 0) nz = 0;
        for (int i = t; i < NBIN; i += 1024) h[i] = 0;
        __syncthreads();
        if (t < 1024 && ei[2 * t + 1] != 0) atomicAdd(&nz, 1);
        __syncthreads();
        const int is64 = (nz == 0) ? 1 : 0;

        const int e0 = blockIdx.x * SEPB + t;
        int d[16], s[16];
#pragma unroll
        for (int k = 0; k < 16; ++k) {
            int e = e0 + k * 1024;
            if (e < NE) {
                d[k] = is64 ? ei[2 * (NE + e)] : ei[NE + e];
                s[k] = is64 ? ei[2 * e]        : ei[e];
                atomicAdd(&h[d[k] >> BINSH], 1);
            } else {
                d[k] = -1; s[k] = 0;
            }
        }
        __syncthreads();
        for (int i = t; i < NBIN; i += 1024) {
            int c = h[i];
            lbase[i] = c ? atomicAdd(&bincur[i], c) : 0;
            h[i] = 0;                  // reuse as intra-block rank counter
        }
        __syncthreads();
#pragma unroll
        for (int k = 0; k < 16; ++k) {
            if (d[k] >= 0) {
                int b = d[k] >> BINSH;
                int r = atomicAdd(&h[b], 1);
                pairs[(size_t)b * BCAP + lbase[b] + r] =
                    ((d[k] & 127) << 17) | s[k];
            }
        }
    } else {
        // ---- x fp32 -> bf16 (grid-stride over the 414 non-scatter blocks)
        const int tid0 = (blockIdx.x - SC_BLKS) * 1024 + t;
        const int stride = (PRE_BLKS - SC_BLKS) * 1024;
        for (int i = tid0; i < N_NODES * 128 / 4; i += stride) {
            float4 v = x4[i];
            ushort4 o;
            o.x = bf_bits(v.x); o.y = bf_bits(v.y);
            o.z = bf_bits(v.z); o.w = bf_bits(v.w);
            xb4[i] = o;
        }
    }
}

// ---------------------------------------------------------------------------
// FUSED per-bin CSR build + 128-dim mean gather (2 blocks/bin) PLUS
// AGG_EXTRA trailing blocks doing W->bf16 + dropout mask (pure VALU/stream
// work that hides under the memory-bound gather; consumed only by lin1f).
// ---------------------------------------------------------------------------
__global__ __launch_bounds__(1024) void k_aggcsr(
        const __hip_bfloat16* __restrict__ feat,
        const int* __restrict__ pairs, const int* __restrict__ bincnt,
        int* __restrict__ ptr, int* __restrict__ adj,
        __hip_bfloat16* __restrict__ mean,
        const float* __restrict__ W1l, const float* __restrict__ W1r,
        const float* __restrict__ W2l, const float* __restrict__ W2r,
        __hip_bfloat16* __restrict__ wb, unsigned long long* __restrict__ km) {
    if (blockIdx.x >= NBIN * 2) {
        // ---- overlap blocks: W conv + threefry mask -----------------------
        const int tid0 = (blockIdx.x - NBIN * 2) * 1024 + threadIdx.x;
        const int stride = AGG_EXTRA * 1024;
        for (int i = tid0; i < 49152; i += stride) {
            float v;
            if (i < 16384)      v = W1l[i];
            else if (i < 32768) v = W1r[i - 16384];
            else if (i < 40960) v = W2l[i - 32768];
            else                v = W2r[i - 40960];
            wb[i] = __float2bfloat16(v);
        }
        const int lane = threadIdx.x & 63;
        const int gw = tid0 >> 6;
        const int nw = stride >> 6;
        for (int widx = gw; widx < NMASKW; widx += nw) {
            unsigned wv = tf_word((unsigned)widx * 64u + (unsigned)lane);
            unsigned long long keep = __ballot(!(wv & 0x80000000u));
            if (lane == 0) km[widx] = keep;
        }
        return;
    }

    __shared__ int ladj[BCAP];
    __shared__ int cnt[128];
    __shared__ int sc[128];
    __shared__ int woff[128];
    __shared__ int red[16];
    __shared__ int base_s;
    const int b = blockIdx.x >> 1;
    const int hb = blockIdx.x & 1;     // which 64-node half this block owns
    const int t = threadIdx.x;

    // ---- base = sum bincnt[0..b) ------------------------------------------
    int s = 0;
    for (int i = t; i < b; i += 1024) s += bincnt[i];
#pragma unroll
    for (int off = 32; off > 0; off >>= 1) s += __shfl_down(s, off);
    if ((t & 63) == 0) red[t >> 6] = s;
    if (t < 128) cnt[t] = 0;
    __syncthreads();
    if (t == 0) {
        int tot = 0;
#pragma unroll
        for (int i = 0; i < 16; ++i) tot += red[i];
        base_s = tot;
    }
    __syncthreads();
    const int base = base_s;
    const int nb = bincnt[b];
    const int* pb = pairs + (size_t)b * BCAP;

    // ---- count + scan (duplicated across the block pair) ------------------
    for (int i = t; i < nb; i += 1024)
        atomicAdd(&cnt[(pb[i] >> 17) & 127], 1);
    __syncthreads();
    if (t < 128) sc[t] = cnt[t];
    __syncthreads();
    for (int o = 1; o < 128; o <<= 1) {
        int u = 0;
        if (t < 128 && t >= o) u = sc[t - o];
        __syncthreads();
        if (t < 128) sc[t] += u;
        __syncthreads();
    }
    if (t < 128) {
        int ex = sc[t] - cnt[t];
        int node = b * 128 + t;
        if (hb == ((t >> 6) & 1) && node <= N_NODES) ptr[node] = base + ex;
        woff[t] = ex;
    }
    __syncthreads();
    // ---- scatter own half into LDS ladj + global adj ----------------------
    for (int i = t; i < nb; i += 1024) {
        int pk = pb[i];
        int dl = (pk >> 17) & 127;
        if ((dl >> 6) == hb) {
            int r = atomicAdd(&woff[dl], 1);
            int src = pk & 0x1FFFF;
            ladj[r] = src;
            adj[base + r] = src;
        }
    }
    __syncthreads();

    // ---- gather: wave w handles local nodes hb*64 + w*4 .. +3 -------------
    const int w = t >> 6;
    const int l = t & 63;
    const int half = l >> 5;
    const size_t coff = (size_t)(l & 31) * 4;
    for (int i = 0; i < 4; ++i) {
        const int local = hb * 64 + w * 4 + i;
        const int node = b * 128 + local;
        if (node >= N_NODES) continue;
        const int p1 = sc[local];
        const int p0 = p1 - cnt[local];
        float c0 = 0.f, c1 = 0.f, c2 = 0.f, c3 = 0.f;
        float d0 = 0.f, d1 = 0.f, d2 = 0.f, d3 = 0.f;
        int p = p0;
        for (; p + 15 < p1; p += 16) {
            int sx[8];
#pragma unroll
            for (int k = 0; k < 8; ++k) sx[k] = ladj[p + 2 * k + half];
#pragma unroll
            for (int k = 0; k < 8; ++k) {
                uint2 u = *(const uint2*)(feat + (size_t)sx[k] * 128 + coff);
                if (k & 1) { d0 += BFLO(u.x); d1 += BFHI(u.x); d2 += BFLO(u.y); d3 += BFHI(u.y); }
                else       { c0 += BFLO(u.x); c1 += BFHI(u.x); c2 += BFLO(u.y); c3 += BFHI(u.y); }
            }
        }
        for (; p + 7 < p1; p += 8) {
            int sx[4];
#pragma unroll
            for (int k = 0; k < 4; ++k) sx[k] = ladj[p + 2 * k + half];
#pragma unroll
            for (int k = 0; k < 4; ++k) {
                uint2 u = *(const uint2*)(feat + (size_t)sx[k] * 128 + coff);
                if (k & 1) { d0 += BFLO(u.x); d1 += BFHI(u.x); d2 += BFLO(u.y); d3 += BFHI(u.y); }
                else       { c0 += BFLO(u.x); c1 += BFHI(u.x); c2 += BFLO(u.y); c3 += BFHI(u.y); }
            }
        }
        for (; p + 1 < p1; p += 2) {
            int sx = ladj[p + half];
            uint2 u = *(const uint2*)(feat + (size_t)sx * 128 + coff);
            c0 += BFLO(u.x); c1 += BFHI(u.x); c2 += BFLO(u.y); c3 += BFHI(u.y);
        }
        if (p < p1 && half == 0) {
            int sx = ladj[p];
            uint2 u = *(const uint2*)(feat + (size_t)sx * 128 + coff);
            c0 += BFLO(u.x); c1 += BFHI(u.x); c2 += BFLO(u.y); c3 += BFHI(u.y);
        }
        c0 += d0; c1 += d1; c2 += d2; c3 += d3;
        c0 += __shfl_xor(c0, 32);
        c1 += __shfl_xor(c1, 32);
        c2 += __shfl_xor(c2, 32);
        c3 += __shfl_xor(c3, 32);
        if (half == 0) {
            const float inv = 1.0f / (float)max(p1 - p0, 1);
            uint2 o;
            o.x = ((unsigned)bf_bits(c1 * inv) << 16) | (unsigned)bf_bits(c0 * inv);
            o.y = ((unsigned)bf_bits(c3 * inv) << 16) | (unsigned)bf_bits(c2 * inv);
            *(uint2*)(mean + (size_t)node * 128 + coff) = o;
        }
    }
}

// ---------------------------------------------------------------------------
// Fused layer1 + layer2-projections (64-row structure) with LDS-STAGED
// coalesced y2/zb stores (was: 32 scattered 2-byte stores per thread).
//   h = dropout(relu(mean·W1l^T + x·W1r^T + b1))   (LDS only)
//   y2 = h·W2l^T (bf16)   z = h·W2r^T + b2 (bf16 scratch; agg2f finishes)
// MFMA 16x16x32 bf16; C/D: col=lane&15, row=(lane>>4)*4+reg  [m89].
// ---------------------------------------------------------------------------
__global__ __launch_bounds__(256) void k_lin1f(
    const __hip_bfloat16* __restrict__ Am, const __hip_bfloat16* __restrict__ Ax,
    const __hip_bfloat16* __restrict__ W1l, const __hip_bfloat16* __restrict__ W1r,
    const float* __restrict__ b1,
    const __hip_bfloat16* __restrict__ W2l, const __hip_bfloat16* __restrict__ W2r,
    const float* __restrict__ b2,
    const unsigned long long* __restrict__ kmask,
    __hip_bfloat16* __restrict__ y2, __hip_bfloat16* __restrict__ zb) {
    __shared__ __align__(16) __hip_bfloat16 hs[64][136];   // +8 pad: bank spread
    __shared__ __align__(16) unsigned short sy[16][68];
    __shared__ __align__(16) unsigned short sz[16][68];
    const int tid = threadIdx.x;
    const int w  = tid >> 6;
    const int l  = tid & 63;
    const int lr = l & 15;
    const int lk = l >> 4;
    const int j0 = w * 32;           // phase-1 h-cols owned by this wave
    const int j2 = w * 16 + lr;      // phase-2 out-col
    const int n0 = blockIdx.x * 64;

    bfrag B1[2][2][4];
#pragma unroll
    for (int jt = 0; jt < 2; ++jt) {
        const int jrow = j0 + jt * 16 + lr;
#pragma unroll
        for (int ks = 0; ks < 4; ++ks) {
            B1[jt][0][ks] = *(const bfrag*)(W1l + jrow * 128 + ks * 32 + lk * 8);
            B1[jt][1][ks] = *(const bfrag*)(W1r + jrow * 128 + ks * 32 + lk * 8);
        }
    }
    bfrag Bl2[4], Br2[4];
#pragma unroll
    for (int ks = 0; ks < 4; ++ks) {
        Bl2[ks] = *(const bfrag*)(W2l + j2 * 128 + ks * 32 + lk * 8);
        Br2[ks] = *(const bfrag*)(W2r + j2 * 128 + ks * 32 + lk * 8);
    }
    const float bj0 = b1[j0 + lr];
    const float bj1 = b1[j0 + 16 + lr];
    const float bj2 = b2[j2];

    // ---- phase 1: h tile -> LDS -------------------------------------------
    for (int t = 0; t < 4; ++t) {
        const int rbase = n0 + t * 16;
        int arow = rbase + lr;
        if (arow > N_NODES - 1) arow = N_NODES - 1;
        ffrag acc0 = {0.f, 0.f, 0.f, 0.f};
        ffrag acc1 = {0.f, 0.f, 0.f, 0.f};
#pragma unroll
        for (int ks = 0; ks < 4; ++ks) {
            bfrag am = *(const bfrag*)(Am + (size_t)arow * 128 + ks * 32 + lk * 8);
            bfrag ax = *(const bfrag*)(Ax + (size_t)arow * 128 + ks * 32 + lk * 8);
            acc0 = __builtin_amdgcn_mfma_f32_16x16x32_bf16(am, B1[0][0][ks], acc0, 0, 0, 0);
            acc1 = __builtin_amdgcn_mfma_f32_16x16x32_bf16(am, B1[1][0][ks], acc1, 0, 0, 0);
            acc0 = __builtin_amdgcn_mfma_f32_16x16x32_bf16(ax, B1[0][1][ks], acc0, 0, 0, 0);
            acc1 = __builtin_amdgcn_mfma_f32_16x16x32_bf16(ax, B1[1][1][ks], acc1, 0, 0, 0);
        }
#pragma unroll
        for (int r = 0; r < 4; ++r) {
            const int n = rbase + lk * 4 + r;
            const int lrow = t * 16 + lk * 4 + r;
            const int nm = (n < N_NODES) ? n : (N_NODES - 1);
            const unsigned long long km = kmask[nm * 2 + (j0 >> 6)];
            float v0 = fmaxf(acc0[r] + bj0, 0.f);
            v0 = ((km >> ((j0 + lr) & 63)) & 1ull) ? (v0 + v0) : 0.f;
            hs[lrow][j0 + lr] = __float2bfloat16(v0);
            float v1 = fmaxf(acc1[r] + bj1, 0.f);
            v1 = ((km >> ((j0 + 16 + lr) & 63)) & 1ull) ? (v1 + v1) : 0.f;
            hs[lrow][j0 + 16 + lr] = __float2bfloat16(v1);
        }
    }
    __syncthreads();

    // ---- phase 2: y2 = h·W2l^T, z = h·W2r^T + b2, staged stores -----------
    for (int t = 0; t < 4; ++t) {
        ffrag accY = {0.f, 0.f, 0.f, 0.f};
        ffrag accZ = {0.f, 0.f, 0.f, 0.f};
#pragma unroll
        for (int ks = 0; ks < 4; ++ks) {
            bfrag ah = *(const bfrag*)&hs[t * 16 + lr][ks * 32 + lk * 8];
            accY = __builtin_amdgcn_mfma_f32_16x16x32_bf16(ah, Bl2[ks], accY, 0, 0, 0);
            accZ = __builtin_amdgcn_mfma_f32_16x16x32_bf16(ah, Br2[ks], accZ, 0, 0, 0);
        }
#pragma unroll
        for (int r = 0; r < 4; ++r) {
            sy[lk * 4 + r][j2] = bf_bits(accY[r]);
            sz[lk * 4 + r][j2] = bf_bits(accZ[r] + bj2);
        }
        __syncthreads();
        // coalesced copy-out: 16 threads/row x ushort4 = 128B per row
        {
            const int row = tid >> 4;
            const int c4 = (tid & 15) * 4;
            const int n = n0 + t * 16 + row;
            if (n < N_NODES) {
                ushort4 vy = *(const ushort4*)&sy[row][c4];
                ushort4 vz = *(const ushort4*)&sz[row][c4];
                *(ushort4*)((unsigned short*)y2 + (size_t)n * 64 + c4) = vy;
                *(ushort4*)((unsigned short*)zb + (size_t)n * 64 + c4) = vz;
            }
        }
        __syncthreads();
    }
}

// ---------------------------------------------------------------------------
// Layer-2 gather+finish: out[n][:] = z[n][:] + mean_{nbr} y2[nbr][:]
// z read as bf16 scratch; out is a pure coalesced fp32 write (no RMW).
// ---------------------------------------------------------------------------
__global__ void k_agg2f(const __hip_bfloat16* __restrict__ feat,
                        const int* __restrict__ ptr, const int* __restrict__ adj,
                        const __hip_bfloat16* __restrict__ zb,
                        float* __restrict__ out) {
    const int node = (blockIdx.x * blockDim.x + threadIdx.x) >> 5;
    const int sl = threadIdx.x & 31;
    if (node >= N_NODES) return;
    const int p0 = ptr[node], p1 = ptr[node + 1];
    const int sub = sl >> 4;
    const size_t coff = (size_t)(sl & 15) * 4;
    float c0 = 0.f, c1 = 0.f, c2 = 0.f, c3 = 0.f;
    float d0 = 0.f, d1 = 0.f, d2 = 0.f, d3 = 0.f;
    int p = p0;
    for (; p + 15 < p1; p += 16) {
        int s[8];
#pragma unroll
        for (int k = 0; k < 8; ++k) s[k] = adj[p + 2 * k + sub];
#pragma unroll
        for (int k = 0; k < 8; ++k) {
            uint2 u = *(const uint2*)(feat + (size_t)s[k] * 64 + coff);
            if (k & 1) { d0 += BFLO(u.x); d1 += BFHI(u.x); d2 += BFLO(u.y); d3 += BFHI(u.y); }
            else       { c0 += BFLO(u.x); c1 += BFHI(u.x); c2 += BFLO(u.y); c3 += BFHI(u.y); }
        }
    }
    for (; p + 7 < p1; p += 8) {
        int s[4];
#pragma unroll
        for (int k = 0; k < 4; ++k) s[k] = adj[p + 2 * k + sub];
#pragma unroll
        for (int k = 0; k < 4; ++k) {
            uint2 u = *(const uint2*)(feat + (size_t)s[k] * 64 + coff);
            if (k & 1) { d0 += BFLO(u.x); d1 += BFHI(u.x); d2 += BFLO(u.y); d3 += BFHI(u.y); }
            else       { c0 += BFLO(u.x); c1 += BFHI(u.x); c2 += BFLO(u.y); c3 += BFHI(u.y); }
        }
    }
    for (; p + 1 < p1; p += 2) {
        int s = adj[p + sub];
        uint2 u = *(const uint2*)(feat + (size_t)s * 64 + coff);
        c0 += BFLO(u.x); c1 += BFHI(u.x); c2 += BFLO(u.y); c3 += BFHI(u.y);
    }
    if (p < p1 && sub == 0) {
        int s = adj[p];
        uint2 u = *(const uint2*)(feat + (size_t)s * 64 + coff);
        c0 += BFLO(u.x); c1 += BFHI(u.x); c2 += BFLO(u.y); c3 += BFHI(u.y);
    }
    c0 += d0; c1 += d1; c2 += d2; c3 += d3;
    c0 += __shfl_xor(c0, 16);
    c1 += __shfl_xor(c1, 16);
    c2 += __shfl_xor(c2, 16);
    c3 += __shfl_xor(c3, 16);
    if (sub == 0) {
        const float inv = 1.0f / (float)max(p1 - p0, 1);
        uint2 zu = *(const uint2*)(zb + (size_t)node * 64 + coff);
        float4 o;
        o.x = BFLO(zu.x) + c0 * inv;
        o.y = BFHI(zu.x) + c1 * inv;
        o.z = BFLO(zu.y) + c2 * inv;
        o.w = BFHI(zu.y) + c3 * inv;
        *(float4*)(out + (size_t)node * 64 + coff) = o;
    }
}

// ---------------------------------------------------------------------------
extern "C" void kernel_launch(void* const* d_in, const int* in_sizes, int n_in,
                              void* d_out, int out_size, void* d_ws, size_t ws_size,
                              hipStream_t stream) {
    const float* x   = (const float*)d_in[0];
    const int*   ei  = (const int*)d_in[1];
    const float* W1l = (const float*)d_in[2];
    const float* b1  = (const float*)d_in[3];
    const float* W1r = (const float*)d_in[4];
    const float* W2l = (const float*)d_in[5];
    const float* b2  = (const float*)d_in[6];
    const float* W2r = (const float*)d_in[7];
    float* out = (float*)d_out;

    char* w = (char*)d_ws;
    int* bincur = (int*)w + 64;                  // 1024 (NBIN used; counts after scatter)
    int* ptr    = bincur + 1024;                 // N+1
    int* adj    = ptr + (N_NODES + 1);           // NE
    size_t koff = (((size_t)(64 + 1024 + N_NODES + 1 + NE)) * 4 + 255)
                  & ~(size_t)255;
    unsigned long long* kmask = (unsigned long long*)(w + koff);  // 200000 ull
    size_t foff = (koff + (size_t)NMASKW * 8 + 255) & ~(size_t)255;
    __hip_bfloat16* wb    = (__hip_bfloat16*)(w + foff);        // 49152
    __hip_bfloat16* w1lb  = wb;
    __hip_bfloat16* w1rb  = wb + 16384;
    __hip_bfloat16* w2lb  = wb + 32768;
    __hip_bfloat16* w2rb  = wb + 40960;
    __hip_bfloat16* xb    = wb + 49152;                         // N*128
    __hip_bfloat16* meanb = xb + (size_t)N_NODES * 128;         // N*128
    char* pregion = (char*)(meanb + (size_t)N_NODES * 128);
    int* pairs = (int*)pregion;                      // 9.6 MB, dead after aggcsr
    __hip_bfloat16* y2b = (__hip_bfloat16*)pregion;  // [N,64] overlay (12.8 MB)
    __hip_bfloat16* zbb = y2b + (size_t)N_NODES * 64; // [N,64] bf16 z (12.8 MB)

    hipMemsetAsync(bincur, 0, 1024 * sizeof(int), stream);

    k_prescatter<<<PRE_BLKS, 1024, 0, stream>>>(ei, bincur, pairs,
                                                (const float4*)x, (ushort4*)xb);

    k_aggcsr<<<NBIN * 2 + AGG_EXTRA, 1024, 0, stream>>>(
        xb, pairs, bincur, ptr, adj, meanb,
        W1l, W1r, W2l, W2r, wb, kmask);

    const int nb  = (N_NODES + 63) / 64;         // k_lin1f: 1563 blocks (64-row)
    const int ab2 = (N_NODES + 7) / 8;           // k_agg2f: 8 nodes / 256-block

    k_lin1f<<<nb, 256, 0, stream>>>(meanb, xb, w1lb, w1rb, b1,
                                    w2lb, w2rb, b2, kmask, y2b, zbb);
    k_agg2f<<<ab2, 256, 0, stream>>>(y2b, ptr, adj, zbb, out);
}

// Round 15
// 219.883 us; speedup vs baseline: 1.1723x; 1.1723x over previous
//
#include <hip/hip_runtime.h>
#include <hip/hip_bf16.h>

#define N_NODES 100000
#define NE      1600000

#define BINSH 7
#define NBIN  782                      // ceil(100000 / 128)
#define BCAP  3072                     // max edges/bin (avg 2046, sigma~45)
#define SEPB  16384                    // edges per binning block
#define SC_BLKS ((NE + SEPB - 1) / SEPB)   // 98 scatter blocks
#define PRE_BLKS 512
#define NMASKW 200000                  // 12.8M dropout bits / 64

typedef __attribute__((ext_vector_type(8))) short bfrag;   // 8 bf16 (4 VGPR)
typedef __attribute__((ext_vector_type(4))) float ffrag;   // 4 fp32 acc

#define BFLO(u) __uint_as_float((u) << 16)
#define BFHI(u) __uint_as_float((u) & 0xffff0000u)

// ---------------------------------------------------------------------------
// JAX threefry2x32, partitionable path. key=(0,42), counter=(0,f),
// bits = out0 ^ out1, keep <=> top bit == 0.
// ---------------------------------------------------------------------------
__device__ __forceinline__ unsigned tf_rotl(unsigned x, int d) {
    return (x << d) | (x >> (32 - d));
}

__device__ __forceinline__ unsigned tf_word(unsigned f) {
    const unsigned ks0 = 0u;
    const unsigned ks1 = 42u;
    const unsigned ks2 = 0x1BD11BDAu ^ 0u ^ 42u;
    unsigned x0 = 0u + ks0;
    unsigned x1 = f + ks1;
#define TF_RND(r) { x0 += x1; x1 = tf_rotl(x1, r); x1 ^= x0; }
    TF_RND(13) TF_RND(15) TF_RND(26) TF_RND(6)
    x0 += ks1; x1 += ks2 + 1u;
    TF_RND(17) TF_RND(29) TF_RND(16) TF_RND(24)
    x0 += ks2; x1 += ks0 + 2u;
    TF_RND(13) TF_RND(15) TF_RND(26) TF_RND(6)
    x0 += ks0; x1 += ks1 + 3u;
    TF_RND(17) TF_RND(29) TF_RND(16) TF_RND(24)
    x0 += ks1; x1 += ks2 + 4u;
    TF_RND(13) TF_RND(15) TF_RND(26) TF_RND(6)
    x0 += ks2; x1 += ks0 + 5u;
#undef TF_RND
    return x0 ^ x1;
}

__device__ __forceinline__ unsigned short bf_bits(float v) {
    __hip_bfloat16 b = __float2bfloat16(v);
    return *(unsigned short*)&b;
}

// ---------------------------------------------------------------------------
// FUSED preprocessing + binned edge scatter (512 blocks x 1024) — r13 form:
//   blocks 0..97:   per-block dtype probe + edge scatter into fixed-cap bins
//   blocks 98..511: x->bf16, W->bf16, dropout mask (grid-stride)
// ---------------------------------------------------------------------------
__global__ __launch_bounds__(1024) void k_prescatter(
    const int* __restrict__ ei, int* __restrict__ bincur, int* __restrict__ pairs,
    const float4* __restrict__ x4, ushort4* __restrict__ xb4,
    const float* __restrict__ W1l, const float* __restrict__ W1r,
    const float* __restrict__ W2l, const float* __restrict__ W2r,
    __hip_bfloat16* __restrict__ wb, unsigned long long* __restrict__ km) {
    const int t = threadIdx.x;

    if (blockIdx.x < SC_BLKS) {
        __shared__ int nz;
        __shared__ int h[NBIN];
        __shared__ int lbase[NBIN];
        if (t == 0) nz = 0;
        for (int i = t; i < NBIN; i += 1024) h[i] = 0;
        __syncthreads();
        if (t < 1024 && ei[2 * t + 1] != 0) atomicAdd(&nz, 1);
        __syncthreads();
        const int is64 = (nz == 0) ? 1 : 0;

        const int e0 = blockIdx.x * SEPB + t;
        int d[16], s[16];
#pragma unroll
        for (int k = 0; k < 16; ++k) {
            int e = e0 + k * 1024;
            if (e < NE) {
                d[k] = is64 ? ei[2 * (NE + e)] : ei[NE + e];
                s[k] = is64 ? ei[2 * e]        : ei[e];
                atomicAdd(&h[d[k] >> BINSH], 1);
            } else {
                d[k] = -1; s[k] = 0;
            }
        }
        __syncthreads();
        for (int i = t; i < NBIN; i += 1024) {
            int c = h[i];
            lbase[i] = c ? atomicAdd(&bincur[i], c) : 0;
            h[i] = 0;                  // reuse as intra-block rank counter
        }
        __syncthreads();
#pragma unroll
        for (int k = 0; k < 16; ++k) {
            if (d[k] >= 0) {
                int b = d[k] >> BINSH;
                int r = atomicAdd(&h[b], 1);
                pairs[(size_t)b * BCAP + lbase[b] + r] =
                    ((d[k] & 127) << 17) | s[k];
            }
        }
    } else {
        // ---- conv + W + mask (grid-stride over the 414 non-scatter blocks)
        const int tid0 = (blockIdx.x - SC_BLKS) * 1024 + t;
        const int stride = (PRE_BLKS - SC_BLKS) * 1024;
        for (int i = tid0; i < N_NODES * 128 / 4; i += stride) {
            float4 v = x4[i];
            ushort4 o;
            o.x = bf_bits(v.x); o.y = bf_bits(v.y);
            o.z = bf_bits(v.z); o.w = bf_bits(v.w);
            xb4[i] = o;
        }
        for (int i = tid0; i < 49152; i += stride) {
            float v;
            if (i < 16384)      v = W1l[i];
            else if (i < 32768) v = W1r[i - 16384];
            else if (i < 40960) v = W2l[i - 32768];
            else                v = W2r[i - 40960];
            wb[i] = __float2bfloat16(v);
        }
        const int lane = t & 63;
        const int gw = tid0 >> 6;
        const int nw = stride >> 6;
        for (int widx = gw; widx < NMASKW; widx += nw) {
            unsigned wv = tf_word((unsigned)widx * 64u + (unsigned)lane);
            unsigned long long keep = __ballot(!(wv & 0x80000000u));
            if (lane == 0) km[widx] = keep;
        }
    }
}

// ---------------------------------------------------------------------------
// FUSED per-bin CSR build + 128-dim mean gather; TWO blocks per bin
// (1564 blocks x 1024 thr) — r13 form (no guest blocks; r14's in-kernel
// mask blocks halved gather bandwidth, reverted).
// ---------------------------------------------------------------------------
__global__ __launch_bounds__(1024) void k_aggcsr(
        const __hip_bfloat16* __restrict__ feat,
        const int* __restrict__ pairs, const int* __restrict__ bincnt,
        int* __restrict__ ptr, int* __restrict__ adj,
        __hip_bfloat16* __restrict__ mean) {
    __shared__ int ladj[BCAP];
    __shared__ int cnt[128];
    __shared__ int sc[128];
    __shared__ int woff[128];
    __shared__ int red[16];
    __shared__ int base_s;
    const int b = blockIdx.x >> 1;
    const int hb = blockIdx.x & 1;     // which 64-node half this block owns
    const int t = threadIdx.x;

    // ---- base = sum bincnt[0..b) ------------------------------------------
    int s = 0;
    for (int i = t; i < b; i += 1024) s += bincnt[i];
#pragma unroll
    for (int off = 32; off > 0; off >>= 1) s += __shfl_down(s, off);
    if ((t & 63) == 0) red[t >> 6] = s;
    if (t < 128) cnt[t] = 0;
    __syncthreads();
    if (t == 0) {
        int tot = 0;
#pragma unroll
        for (int i = 0; i < 16; ++i) tot += red[i];
        base_s = tot;
    }
    __syncthreads();
    const int base = base_s;
    const int nb = bincnt[b];
    const int* pb = pairs + (size_t)b * BCAP;

    // ---- count + scan (duplicated across the block pair) ------------------
    for (int i = t; i < nb; i += 1024)
        atomicAdd(&cnt[(pb[i] >> 17) & 127], 1);
    __syncthreads();
    if (t < 128) sc[t] = cnt[t];
    __syncthreads();
    for (int o = 1; o < 128; o <<= 1) {
        int u = 0;
        if (t < 128 && t >= o) u = sc[t - o];
        __syncthreads();
        if (t < 128) sc[t] += u;
        __syncthreads();
    }
    if (t < 128) {
        int ex = sc[t] - cnt[t];
        int node = b * 128 + t;
        if (hb == ((t >> 6) & 1) && node <= N_NODES) ptr[node] = base + ex;
        woff[t] = ex;
    }
    __syncthreads();
    // ---- scatter own half into LDS ladj + global adj ----------------------
    for (int i = t; i < nb; i += 1024) {
        int pk = pb[i];
        int dl = (pk >> 17) & 127;
        if ((dl >> 6) == hb) {
            int r = atomicAdd(&woff[dl], 1);
            int src = pk & 0x1FFFF;
            ladj[r] = src;
            adj[base + r] = src;
        }
    }
    __syncthreads();

    // ---- gather: wave w handles local nodes hb*64 + w*4 .. +3 -------------
    const int w = t >> 6;
    const int l = t & 63;
    const int half = l >> 5;
    const size_t coff = (size_t)(l & 31) * 4;
    for (int i = 0; i < 4; ++i) {
        const int local = hb * 64 + w * 4 + i;
        const int node = b * 128 + local;
        if (node >= N_NODES) continue;
        const int p1 = sc[local];
        const int p0 = p1 - cnt[local];
        float c0 = 0.f, c1 = 0.f, c2 = 0.f, c3 = 0.f;
        float d0 = 0.f, d1 = 0.f, d2 = 0.f, d3 = 0.f;
        int p = p0;
        for (; p + 15 < p1; p += 16) {
            int sx[8];
#pragma unroll
            for (int k = 0; k < 8; ++k) sx[k] = ladj[p + 2 * k + half];
#pragma unroll
            for (int k = 0; k < 8; ++k) {
                uint2 u = *(const uint2*)(feat + (size_t)sx[k] * 128 + coff);
                if (k & 1) { d0 += BFLO(u.x); d1 += BFHI(u.x); d2 += BFLO(u.y); d3 += BFHI(u.y); }
                else       { c0 += BFLO(u.x); c1 += BFHI(u.x); c2 += BFLO(u.y); c3 += BFHI(u.y); }
            }
        }
        for (; p + 7 < p1; p += 8) {
            int sx[4];
#pragma unroll
            for (int k = 0; k < 4; ++k) sx[k] = ladj[p + 2 * k + half];
#pragma unroll
            for (int k = 0; k < 4; ++k) {
                uint2 u = *(const uint2*)(feat + (size_t)sx[k] * 128 + coff);
                if (k & 1) { d0 += BFLO(u.x); d1 += BFHI(u.x); d2 += BFLO(u.y); d3 += BFHI(u.y); }
                else       { c0 += BFLO(u.x); c1 += BFHI(u.x); c2 += BFLO(u.y); c3 += BFHI(u.y); }
            }
        }
        for (; p + 1 < p1; p += 2) {
            int sx = ladj[p + half];
            uint2 u = *(const uint2*)(feat + (size_t)sx * 128 + coff);
            c0 += BFLO(u.x); c1 += BFHI(u.x); c2 += BFLO(u.y); c3 += BFHI(u.y);
        }
        if (p < p1 && half == 0) {
            int sx = ladj[p];
            uint2 u = *(const uint2*)(feat + (size_t)sx * 128 + coff);
            c0 += BFLO(u.x); c1 += BFHI(u.x); c2 += BFLO(u.y); c3 += BFHI(u.y);
        }
        c0 += d0; c1 += d1; c2 += d2; c3 += d3;
        c0 += __shfl_xor(c0, 32);
        c1 += __shfl_xor(c1, 32);
        c2 += __shfl_xor(c2, 32);
        c3 += __shfl_xor(c3, 32);
        if (half == 0) {
            const float inv = 1.0f / (float)max(p1 - p0, 1);
            uint2 o;
            o.x = ((unsigned)bf_bits(c1 * inv) << 16) | (unsigned)bf_bits(c0 * inv);
            o.y = ((unsigned)bf_bits(c3 * inv) << 16) | (unsigned)bf_bits(c2 * inv);
            *(uint2*)(mean + (size_t)node * 128 + coff) = o;
        }
    }
}

// ---------------------------------------------------------------------------
// Fused layer1 + layer2-projections (64-row structure) with LDS-STAGED
// coalesced y2/zb stores (kept from r14 — likely ~15us win there).
//   h = dropout(relu(mean·W1l^T + x·W1r^T + b1))   (LDS only)
//   y2 = h·W2l^T (bf16)   z = h·W2r^T + b2 (bf16 scratch; agg2f finishes)
// MFMA 16x16x32 bf16; C/D: col=lane&15, row=(lane>>4)*4+reg  [m89].
// ---------------------------------------------------------------------------
__global__ __launch_bounds__(256) void k_lin1f(
    const __hip_bfloat16* __restrict__ Am, const __hip_bfloat16* __restrict__ Ax,
    const __hip_bfloat16* __restrict__ W1l, const __hip_bfloat16* __restrict__ W1r,
    const float* __restrict__ b1,
    const __hip_bfloat16* __restrict__ W2l, const __hip_bfloat16* __restrict__ W2r,
    const float* __restrict__ b2,
    const unsigned long long* __restrict__ kmask,
    __hip_bfloat16* __restrict__ y2, __hip_bfloat16* __restrict__ zb) {
    __shared__ __align__(16) __hip_bfloat16 hs[64][136];   // +8 pad: bank spread
    __shared__ __align__(16) unsigned short sy[16][68];
    __shared__ __align__(16) unsigned short sz[16][68];
    const int tid = threadIdx.x;
    const int w  = tid >> 6;
    const int l  = tid & 63;
    const int lr = l & 15;
    const int lk = l >> 4;
    const int j0 = w * 32;           // phase-1 h-cols owned by this wave
    const int j2 = w * 16 + lr;      // phase-2 out-col
    const int n0 = blockIdx.x * 64;

    bfrag B1[2][2][4];
#pragma unroll
    for (int jt = 0; jt < 2; ++jt) {
        const int jrow = j0 + jt * 16 + lr;
#pragma unroll
        for (int ks = 0; ks < 4; ++ks) {
            B1[jt][0][ks] = *(const bfrag*)(W1l + jrow * 128 + ks * 32 + lk * 8);
            B1[jt][1][ks] = *(const bfrag*)(W1r + jrow * 128 + ks * 32 + lk * 8);
        }
    }
    bfrag Bl2[4], Br2[4];
#pragma unroll
    for (int ks = 0; ks < 4; ++ks) {
        Bl2[ks] = *(const bfrag*)(W2l + j2 * 128 + ks * 32 + lk * 8);
        Br2[ks] = *(const bfrag*)(W2r + j2 * 128 + ks * 32 + lk * 8);
    }
    const float bj0 = b1[j0 + lr];
    const float bj1 = b1[j0 + 16 + lr];
    const float bj2 = b2[j2];

    // ---- phase 1: h tile -> LDS -------------------------------------------
    for (int t = 0; t < 4; ++t) {
        const int rbase = n0 + t * 16;
        int arow = rbase + lr;
        if (arow > N_NODES - 1) arow = N_NODES - 1;
        ffrag acc0 = {0.f, 0.f, 0.f, 0.f};
        ffrag acc1 = {0.f, 0.f, 0.f, 0.f};
#pragma unroll
        for (int ks = 0; ks < 4; ++ks) {
            bfrag am = *(const bfrag*)(Am + (size_t)arow * 128 + ks * 32 + lk * 8);
            bfrag ax = *(const bfrag*)(Ax + (size_t)arow * 128 + ks * 32 + lk * 8);
            acc0 = __builtin_amdgcn_mfma_f32_16x16x32_bf16(am, B1[0][0][ks], acc0, 0, 0, 0);
            acc1 = __builtin_amdgcn_mfma_f32_16x16x32_bf16(am, B1[1][0][ks], acc1, 0, 0, 0);
            acc0 = __builtin_amdgcn_mfma_f32_16x16x32_bf16(ax, B1[0][1][ks], acc0, 0, 0, 0);
            acc1 = __builtin_amdgcn_mfma_f32_16x16x32_bf16(ax, B1[1][1][ks], acc1, 0, 0, 0);
        }
#pragma unroll
        for (int r = 0; r < 4; ++r) {
            const int n = rbase + lk * 4 + r;
            const int lrow = t * 16 + lk * 4 + r;
            const int nm = (n < N_NODES) ? n : (N_NODES - 1);
            const unsigned long long km = kmask[nm * 2 + (j0 >> 6)];
            float v0 = fmaxf(acc0[r] + bj0, 0.f);
            v0 = ((km >> ((j0 + lr) & 63)) & 1ull) ? (v0 + v0) : 0.f;
            hs[lrow][j0 + lr] = __float2bfloat16(v0);
            float v1 = fmaxf(acc1[r] + bj1, 0.f);
            v1 = ((km >> ((j0 + 16 + lr) & 63)) & 1ull) ? (v1 + v1) : 0.f;
            hs[lrow][j0 + 16 + lr] = __float2bfloat16(v1);
        }
    }
    __syncthreads();

    // ---- phase 2: y2 = h·W2l^T, z = h·W2r^T + b2, staged stores -----------
    for (int t = 0; t < 4; ++t) {
        ffrag accY = {0.f, 0.f, 0.f, 0.f};
        ffrag accZ = {0.f, 0.f, 0.f, 0.f};
#pragma unroll
        for (int ks = 0; ks < 4; ++ks) {
            bfrag ah = *(const bfrag*)&hs[t * 16 + lr][ks * 32 + lk * 8];
            accY = __builtin_amdgcn_mfma_f32_16x16x32_bf16(ah, Bl2[ks], accY, 0, 0, 0);
            accZ = __builtin_amdgcn_mfma_f32_16x16x32_bf16(ah, Br2[ks], accZ, 0, 0, 0);
        }
#pragma unroll
        for (int r = 0; r < 4; ++r) {
            sy[lk * 4 + r][j2] = bf_bits(accY[r]);
            sz[lk * 4 + r][j2] = bf_bits(accZ[r] + bj2);
        }
        __syncthreads();
        // coalesced copy-out: 16 threads/row x ushort4 = 128B per row
        {
            const int row = tid >> 4;
            const int c4 = (tid & 15) * 4;
            const int n = n0 + t * 16 + row;
            if (n < N_NODES) {
                ushort4 vy = *(const ushort4*)&sy[row][c4];
                ushort4 vz = *(const ushort4*)&sz[row][c4];
                *(ushort4*)((unsigned short*)y2 + (size_t)n * 64 + c4) = vy;
                *(ushort4*)((unsigned short*)zb + (size_t)n * 64 + c4) = vz;
            }
        }
        __syncthreads();
    }
}

// ---------------------------------------------------------------------------
// Layer-2 gather+finish: out[n][:] = z[n][:] + mean_{nbr} y2[nbr][:]
// z read as bf16 scratch; out is a pure coalesced fp32 write (no RMW).
// ---------------------------------------------------------------------------
__global__ void k_agg2f(const __hip_bfloat16* __restrict__ feat,
                        const int* __restrict__ ptr, const int* __restrict__ adj,
                        const __hip_bfloat16* __restrict__ zb,
                        float* __restrict__ out) {
    const int node = (blockIdx.x * blockDim.x + threadIdx.x) >> 5;
    const int sl = threadIdx.x & 31;
    if (node >= N_NODES) return;
    const int p0 = ptr[node], p1 = ptr[node + 1];
    const int sub = sl >> 4;
    const size_t coff = (size_t)(sl & 15) * 4;
    float c0 = 0.f, c1 = 0.f, c2 = 0.f, c3 = 0.f;
    float d0 = 0.f, d1 = 0.f, d2 = 0.f, d3 = 0.f;
    int p = p0;
    for (; p + 15 < p1; p += 16) {
        int s[8];
#pragma unroll
        for (int k = 0; k < 8; ++k) s[k] = adj[p + 2 * k + sub];
#pragma unroll
        for (int k = 0; k < 8; ++k) {
            uint2 u = *(const uint2*)(feat + (size_t)s[k] * 64 + coff);
            if (k & 1) { d0 += BFLO(u.x); d1 += BFHI(u.x); d2 += BFLO(u.y); d3 += BFHI(u.y); }
            else       { c0 += BFLO(u.x); c1 += BFHI(u.x); c2 += BFLO(u.y); c3 += BFHI(u.y); }
        }
    }
    for (; p + 7 < p1; p += 8) {
        int s[4];
#pragma unroll
        for (int k = 0; k < 4; ++k) s[k] = adj[p + 2 * k + sub];
#pragma unroll
        for (int k = 0; k < 4; ++k) {
            uint2 u = *(const uint2*)(feat + (size_t)s[k] * 64 + coff);
            if (k & 1) { d0 += BFLO(u.x); d1 += BFHI(u.x); d2 += BFLO(u.y); d3 += BFHI(u.y); }
            else       { c0 += BFLO(u.x); c1 += BFHI(u.x); c2 += BFLO(u.y); c3 += BFHI(u.y); }
        }
    }
    for (; p + 1 < p1; p += 2) {
        int s = adj[p + sub];
        uint2 u = *(const uint2*)(feat + (size_t)s * 64 + coff);
        c0 += BFLO(u.x); c1 += BFHI(u.x); c2 += BFLO(u.y); c3 += BFHI(u.y);
    }
    if (p < p1 && sub == 0) {
        int s = adj[p];
        uint2 u = *(const uint2*)(feat + (size_t)s * 64 + coff);
        c0 += BFLO(u.x); c1 += BFHI(u.x); c2 += BFLO(u.y); c3 += BFHI(u.y);
    }
    c0 += d0; c1 += d1; c2 += d2; c3 += d3;
    c0 += __shfl_xor(c0, 16);
    c1 += __shfl_xor(c1, 16);
    c2 += __shfl_xor(c2, 16);
    c3 += __shfl_xor(c3, 16);
    if (sub == 0) {
        const float inv = 1.0f / (float)max(p1 - p0, 1);
        uint2 zu = *(const uint2*)(zb + (size_t)node * 64 + coff);
        float4 o;
        o.x = BFLO(zu.x) + c0 * inv;
        o.y = BFHI(zu.x) + c1 * inv;
        o.z = BFLO(zu.y) + c2 * inv;
        o.w = BFHI(zu.y) + c3 * inv;
        *(float4*)(out + (size_t)node * 64 + coff) = o;
    }
}

// ---------------------------------------------------------------------------
extern "C" void kernel_launch(void* const* d_in, const int* in_sizes, int n_in,
                              void* d_out, int out_size, void* d_ws, size_t ws_size,
                              hipStream_t stream) {
    const float* x   = (const float*)d_in[0];
    const int*   ei  = (const int*)d_in[1];
    const float* W1l = (const float*)d_in[2];
    const float* b1  = (const float*)d_in[3];
    const float* W1r = (const float*)d_in[4];
    const float* W2l = (const float*)d_in[5];
    const float* b2  = (const float*)d_in[6];
    const float* W2r = (const float*)d_in[7];
    float* out = (float*)d_out;

    char* w = (char*)d_ws;
    int* bincur = (int*)w + 64;                  // 1024 (NBIN used; counts after scatter)
    int* ptr    = bincur + 1024;                 // N+1
    int* adj    = ptr + (N_NODES + 1);           // NE
    size_t koff = (((size_t)(64 + 1024 + N_NODES + 1 + NE)) * 4 + 255)
                  & ~(size_t)255;
    unsigned long long* kmask = (unsigned long long*)(w + koff);  // 200000 ull
    size_t foff = (koff + (size_t)NMASKW * 8 + 255) & ~(size_t)255;
    __hip_bfloat16* wb    = (__hip_bfloat16*)(w + foff);        // 49152
    __hip_bfloat16* w1lb  = wb;
    __hip_bfloat16* w1rb  = wb + 16384;
    __hip_bfloat16* w2lb  = wb + 32768;
    __hip_bfloat16* w2rb  = wb + 40960;
    __hip_bfloat16* xb    = wb + 49152;                         // N*128
    __hip_bfloat16* meanb = xb + (size_t)N_NODES * 128;         // N*128
    char* pregion = (char*)(meanb + (size_t)N_NODES * 128);
    int* pairs = (int*)pregion;                      // 9.6 MB, dead after aggcsr
    __hip_bfloat16* y2b = (__hip_bfloat16*)pregion;  // [N,64] overlay (12.8 MB)
    __hip_bfloat16* zbb = y2b + (size_t)N_NODES * 64; // [N,64] bf16 z (12.8 MB)

    hipMemsetAsync(bincur, 0, 1024 * sizeof(int), stream);

    k_prescatter<<<PRE_BLKS, 1024, 0, stream>>>(ei, bincur, pairs,
                                                (const float4*)x, (ushort4*)xb,
                                                W1l, W1r, W2l, W2r, wb, kmask);

    k_aggcsr<<<NBIN * 2, 1024, 0, stream>>>(xb, pairs, bincur, ptr, adj, meanb);

    const int nb  = (N_NODES + 63) / 64;         // k_lin1f: 1563 blocks (64-row)
    const int ab2 = (N_NODES + 7) / 8;           // k_agg2f: 8 nodes / 256-block

    k_lin1f<<<nb, 256, 0, stream>>>(meanb, xb, w1lb, w1rb, b1,
                                    w2lb, w2rb, b2, kmask, y2b, zbb);
    k_agg2f<<<ab2, 256, 0, stream>>>(y2b, ptr, adj, zbb, out);
}